// Round 1
// baseline (930.854 us; speedup 1.0000x reference)
//
#include <hip/hip_runtime.h>
#include <hip/hip_bf16.h>

#define NCONE 8
#define NDIM 24          // NC*3
#define PGD_ITERS 100
#define BATCH 65536
#define BLOCK 256
#define POW_ITERS 128

__device__ __forceinline__ float fast_sqrt(float x) { return __builtin_amdgcn_sqrtf(x); }
__device__ __forceinline__ float fast_rcp(float x)  { return __builtin_amdgcn_rcpf(x); }

// ---------------------------------------------------------------------------
// Kernel 1: step = 1 / lambda_max(P) via shuffle-based power iteration.
// One wave (64 threads). Lane i (< 24) owns row i of P in registers.
// ---------------------------------------------------------------------------
__global__ __launch_bounds__(64) void eig_step_kernel(const float* __restrict__ P,
                                                      float* __restrict__ step_out) {
    const int lane = threadIdx.x;
    float p[NDIM];
#pragma unroll
    for (int j = 0; j < NDIM; ++j)
        p[j] = (lane < NDIM) ? P[lane * NDIM + j] : 0.0f;

    float v = (lane < NDIM) ? (1.0f + 0.01f * (float)lane) : 0.0f;

    for (int it = 0; it < POW_ITERS; ++it) {
        // w = P v
        float w = 0.0f;
#pragma unroll
        for (int j = 0; j < NDIM; ++j) {
            float vj = __shfl(v, j, 64);
            w = fmaf(p[j], vj, w);
        }
        // n2 = ||w||^2 across lanes (lanes >= 24 contribute 0)
        float n2 = w * w;
#pragma unroll
        for (int off = 32; off >= 1; off >>= 1)
            n2 += __shfl_xor(n2, off, 64);
        v = w * rsqrtf(n2);
    }

    // Rayleigh quotient: lambda = v^T P v / v^T v
    float w = 0.0f;
#pragma unroll
    for (int j = 0; j < NDIM; ++j) {
        float vj = __shfl(v, j, 64);
        w = fmaf(p[j], vj, w);
    }
    float num = v * w;
    float den = v * v;
#pragma unroll
    for (int off = 32; off >= 1; off >>= 1) {
        num += __shfl_xor(num, off, 64);
        den += __shfl_xor(den, off, 64);
    }
    if (lane == 0)
        step_out[0] = den / num;   // 1/lambda
}

// ---------------------------------------------------------------------------
// Kernel 2: batched projected gradient descent.
// One thread per batch element; l,q,g in registers; P broadcast from LDS.
// 256 blocks x 256 threads = 65536 threads = 1 wave/SIMD chip-wide.
// ---------------------------------------------------------------------------
__global__ __launch_bounds__(BLOCK, 1) void pgd_kernel(const float* __restrict__ P,
                                                       const float* __restrict__ q,
                                                       const float* __restrict__ step_ptr,
                                                       float* __restrict__ out) {
    __shared__ float sP[NDIM * NDIM];              // 2304 B
    __shared__ float sQ[BLOCK * (NDIM + 1)];       // stride 25: conflict-free rows

    const int tid  = threadIdx.x;
    const int base = blockIdx.x * BLOCK * NDIM;    // flat element offset

    // Stage P (uniform across block) into LDS.
    for (int i = tid; i < NDIM * NDIM; i += BLOCK)
        sP[i] = P[i];

    // Coalesced load of this block's q slab into padded LDS.
    for (int idx = tid; idx < BLOCK * NDIM; idx += BLOCK) {
        int r = idx / NDIM;
        int c = idx - r * NDIM;
        sQ[r * (NDIM + 1) + c] = q[base + idx];
    }
    __syncthreads();

    float lq[NDIM];
#pragma unroll
    for (int j = 0; j < NDIM; ++j)
        lq[j] = sQ[tid * (NDIM + 1) + j];

    const float step = *step_ptr;

    float l[NDIM];
#pragma unroll
    for (int j = 0; j < NDIM; ++j)
        l[j] = 0.0f;

    for (int it = 0; it < PGD_ITERS; ++it) {
        // g = q + l @ P   (P symmetric; g[j] = sum_i l[i]*P[i][j])
        float g[NDIM];
#pragma unroll
        for (int j = 0; j < NDIM; ++j)
            g[j] = lq[j];
#pragma unroll
        for (int i = 0; i < NDIM; ++i) {
            float li = l[i];
#pragma unroll
            for (int j = 0; j < NDIM; ++j)
                g[j] = fmaf(li, sP[i * NDIM + j], g[j]);
        }
        // y = l - step*g
#pragma unroll
        for (int j = 0; j < NDIM; ++j)
            g[j] = fmaf(-step, g[j], l[j]);

        // Project onto product of 8 second-order cones:
        // cone c: head t = y[c], tail x = y[8+2c : 8+2c+2]
#pragma unroll
        for (int c = 0; c < NCONE; ++c) {
            float t  = g[c];
            float x0 = g[NCONE + 2 * c];
            float x1 = g[NCONE + 2 * c + 1];
            float n  = fast_sqrt(fmaf(x0, x0, x1 * x1));
            float coef   = 0.5f * (t + n);
            float safe_n = (n > 0.0f) ? n : 1.0f;
            float gscale = coef * fast_rcp(safe_n);

            bool inside = (n <= t);
            bool below  = (n <= -t);
            float tn = inside ? t    : (below ? 0.0f : coef);
            float s  = inside ? 1.0f : (below ? 0.0f : gscale);

            l[c]                 = tn;
            l[NCONE + 2 * c]     = x0 * s;
            l[NCONE + 2 * c + 1] = x1 * s;
        }
    }

    // Coalesced store through padded LDS.
    __syncthreads();
#pragma unroll
    for (int j = 0; j < NDIM; ++j)
        sQ[tid * (NDIM + 1) + j] = l[j];
    __syncthreads();
    for (int idx = tid; idx < BLOCK * NDIM; idx += BLOCK) {
        int r = idx / NDIM;
        int c = idx - r * NDIM;
        out[base + idx] = sQ[r * (NDIM + 1) + c];
    }
}

extern "C" void kernel_launch(void* const* d_in, const int* in_sizes, int n_in,
                              void* d_out, int out_size, void* d_ws, size_t ws_size,
                              hipStream_t stream) {
    const float* P = (const float*)d_in[0];   // (1, 24, 24) fp32
    const float* q = (const float*)d_in[1];   // (65536, 24, 1) fp32
    float* out     = (float*)d_out;           // (65536, 24) fp32
    float* step    = (float*)d_ws;            // scratch: step scalar

    eig_step_kernel<<<1, 64, 0, stream>>>(P, step);
    pgd_kernel<<<BATCH / BLOCK, BLOCK, 0, stream>>>(P, q, step, out);
}

// Round 3
// 432.141 us; speedup vs baseline: 2.1541x; 2.1541x over previous
//
#include <hip/hip_runtime.h>

#define NCONE 8
#define NDIM 24          // NC*3
#define PGD_ITERS 100
#define BATCH 65536
#define BLOCKT 128       // threads per block
#define EPB 256          // batch elements per block (2 per thread)
#define POW_ITERS 80

__device__ __forceinline__ float fast_sqrt(float x) { return __builtin_amdgcn_sqrtf(x); }
__device__ __forceinline__ float fast_rcp(float x)  { return __builtin_amdgcn_rcpf(x); }

// SOC projection of one cone (head t, tail (x0,x1)) — matches reference.
__device__ __forceinline__ void soc_proj(float& t, float& x0, float& x1) {
    float n      = fast_sqrt(fmaf(x0, x0, x1 * x1));
    float coef   = 0.5f * (t + n);
    float safe_n = (n > 0.0f) ? n : 1.0f;
    float sc     = coef * fast_rcp(safe_n);
    bool inside  = (n <= t);
    bool below   = (n <= -t);
    float tn = inside ? t    : (below ? 0.0f : coef);
    float s  = inside ? 1.0f : (below ? 0.0f : sc);
    t = tn; x0 *= s; x1 *= s;
}

// ---------------------------------------------------------------------------
// Single fused kernel. R2 lesson: the eig->pgd step handoff through global
// memory diverged after graph capture (poisoned d_ws value observed by pgd
// on replay — cross-XCD visibility of a single dirty line is not a channel
// we can rely on under graph replay). Fix: ZERO inter-block state. Every
// wave redundantly computes step = 1/lambda_max via an in-register power
// iteration (deterministic, bitwise identical everywhere).
//
// Perf (R2 timing): 349 us was LDS-issue-bound — 144 uniform ds_read_b128
// per wave-iter at ~12 cyc each. Here each thread carries TWO batch elements
// (float2), and 256 blocks x 128 threads puts only 2 waves per CU:
// per-CU LDS/iter halves -> ~144 us wall, VALU ~60-110 us overlapped.
// ---------------------------------------------------------------------------
__global__ __launch_bounds__(BLOCKT, 1) void pgd_fused(const float* __restrict__ P,
                                                       const float* __restrict__ q,
                                                       float* __restrict__ out) {
    __shared__ __align__(16) float sP[NDIM * NDIM];   // 2304 B
    __shared__ float sQ[EPB * (NDIM + 1)];            // 25.6 KB, stride 25

    const int tid  = threadIdx.x;
    const int base = blockIdx.x * (EPB * NDIM);

    for (int i = tid; i < NDIM * NDIM; i += BLOCKT)
        sP[i] = P[i];
    for (int idx = tid; idx < EPB * NDIM; idx += BLOCKT) {
        int r = idx / NDIM;
        int c = idx - r * NDIM;
        sQ[r * (NDIM + 1) + c] = q[base + idx];
    }
    __syncthreads();

    // --- step = 1/lambda_max(P): per-wave power iteration + Rayleigh ---
    const int lane = tid & 63;
    float step;
    {
        float p[NDIM];
#pragma unroll
        for (int j = 0; j < NDIM; ++j)
            p[j] = (lane < NDIM) ? sP[lane * NDIM + j] : 0.0f;
        float v = (lane < NDIM) ? (1.0f + 0.01f * (float)lane) : 0.0f;

        for (int it = 0; it < POW_ITERS; ++it) {
            float w = 0.0f;
#pragma unroll
            for (int j = 0; j < NDIM; ++j)
                w = fmaf(p[j], __shfl(v, j, 64), w);
            float n2 = w * w;
#pragma unroll
            for (int off = 32; off >= 1; off >>= 1)
                n2 += __shfl_xor(n2, off, 64);
            v = w * rsqrtf(n2);
        }
        float w = 0.0f;
#pragma unroll
        for (int j = 0; j < NDIM; ++j)
            w = fmaf(p[j], __shfl(v, j, 64), w);
        float num = v * w;
        float den = v * v;
#pragma unroll
        for (int off = 32; off >= 1; off >>= 1) {
            num += __shfl_xor(num, off, 64);
            den += __shfl_xor(den, off, 64);
        }
        step = den / num;   // identical on every lane/wave/block
    }

    // --- two batch elements per thread: rows tid and tid+BLOCKT ---
    float2 lq[NDIM], l[NDIM];
#pragma unroll
    for (int j = 0; j < NDIM; ++j) {
        lq[j] = make_float2(sQ[tid * (NDIM + 1) + j],
                            sQ[(tid + BLOCKT) * (NDIM + 1) + j]);
        l[j]  = make_float2(0.0f, 0.0f);
    }

    const float4* sP4 = (const float4*)sP;

#define FMA2(J, S) do { g[J].x = fmaf(li.x, (S), g[J].x); \
                        g[J].y = fmaf(li.y, (S), g[J].y); } while (0)

#pragma clang loop unroll(disable)
    for (int it = 0; it < PGD_ITERS; ++it) {
        // Pin the (loop-invariant) LDS reads of P inside each iteration —
        // defeats LICM register blowup (R1 lesson).
        asm volatile("" ::: "memory");

        float2 g[NDIM];
#pragma unroll
        for (int j = 0; j < NDIM; ++j)
            g[j] = lq[j];

#pragma unroll
        for (int i = 0; i < NDIM; ++i) {
            float2 li = l[i];
            float4 r0 = sP4[i * 6 + 0];
            float4 r1 = sP4[i * 6 + 1];
            float4 r2 = sP4[i * 6 + 2];
            float4 r3 = sP4[i * 6 + 3];
            float4 r4 = sP4[i * 6 + 4];
            float4 r5 = sP4[i * 6 + 5];
            FMA2(0,  r0.x); FMA2(1,  r0.y); FMA2(2,  r0.z); FMA2(3,  r0.w);
            FMA2(4,  r1.x); FMA2(5,  r1.y); FMA2(6,  r1.z); FMA2(7,  r1.w);
            FMA2(8,  r2.x); FMA2(9,  r2.y); FMA2(10, r2.z); FMA2(11, r2.w);
            FMA2(12, r3.x); FMA2(13, r3.y); FMA2(14, r3.z); FMA2(15, r3.w);
            FMA2(16, r4.x); FMA2(17, r4.y); FMA2(18, r4.z); FMA2(19, r4.w);
            FMA2(20, r5.x); FMA2(21, r5.y); FMA2(22, r5.z); FMA2(23, r5.w);
        }

        // y = l - step*g
#pragma unroll
        for (int j = 0; j < NDIM; ++j) {
            g[j].x = fmaf(-step, g[j].x, l[j].x);
            g[j].y = fmaf(-step, g[j].y, l[j].y);
        }

        // project onto product of 8 SOCs (per element component)
#pragma unroll
        for (int c = 0; c < NCONE; ++c) {
            soc_proj(g[c].x, g[NCONE + 2 * c].x, g[NCONE + 2 * c + 1].x);
            soc_proj(g[c].y, g[NCONE + 2 * c].y, g[NCONE + 2 * c + 1].y);
        }
#pragma unroll
        for (int j = 0; j < NDIM; ++j)
            l[j] = g[j];
    }
#undef FMA2

    // --- coalesced store through padded LDS ---
    __syncthreads();
#pragma unroll
    for (int j = 0; j < NDIM; ++j) {
        sQ[tid * (NDIM + 1) + j]            = l[j].x;
        sQ[(tid + BLOCKT) * (NDIM + 1) + j] = l[j].y;
    }
    __syncthreads();
    for (int idx = tid; idx < EPB * NDIM; idx += BLOCKT) {
        int r = idx / NDIM;
        int c = idx - r * NDIM;
        out[base + idx] = sQ[r * (NDIM + 1) + c];
    }
}

extern "C" void kernel_launch(void* const* d_in, const int* in_sizes, int n_in,
                              void* d_out, int out_size, void* d_ws, size_t ws_size,
                              hipStream_t stream) {
    const float* P = (const float*)d_in[0];   // (1, 24, 24) fp32
    const float* q = (const float*)d_in[1];   // (65536, 24, 1) fp32
    float* out     = (float*)d_out;           // (65536, 24) fp32
    (void)d_ws; (void)ws_size;

    pgd_fused<<<BATCH / EPB, BLOCKT, 0, stream>>>(P, q, out);
}